// Round 5
// baseline (332.007 us; speedup 1.0000x reference)
//
#include <hip/hip_runtime.h>
#include <math.h>

#define NR 7
#define ED 128
#define NUND 500000
#define PITCH 132  // LDS pitch for 128-float rows; 132*4B=528B keeps float4 alignment

typedef float __attribute__((ext_vector_type(4))) fx4;  // NT-store-compatible

// d_ws float layout:
// [0, 896)     M[d*7+k]   = sum_j gamma[j]*Wsw[d,j]*W12[j,k]
// [896, 1024)  wsum[d]    = sum_j gamma[j]*Wsw[d,j]
// [1024, 1152) bb[d]      = sum_j beta[j]*Wsw[d,j]
// [1152, 1201) Q[a*7+b]   = sum_j W12[j,a]*W12[j,b]
// [1201, 1208) m12[k]     = mean_j W12[j,k]

__global__ __launch_bounds__(1024) void precompute_kernel(
    const float* __restrict__ W1, const float* __restrict__ W2,
    const float* __restrict__ gamma, const float* __restrict__ beta,
    const float* __restrict__ Wsw, float* __restrict__ ws)
{
  __shared__ float sBig[ED * PITCH];   // W2, then Wsw
  __shared__ float sW1T[NR * ED];      // W1 transposed: [k][j]
  __shared__ float sW12T[NR * ED];     // W12 transposed: [k][d]
  __shared__ float sGB[2 * ED];        // gamma | beta
  const int t = threadIdx.x;

  if (t < NR * ED) { int k = t >> 7, j = t & 127; sW1T[t] = W1[j * NR + k]; }
  if (t < 2 * ED)  { sGB[t] = (t < ED) ? gamma[t] : beta[t - ED]; }
  {
    const float4* src = (const float4*)W2;
    for (int i = t; i < ED * ED / 4; i += 1024) {
      int row = i >> 5, c4 = i & 31;
      *(float4*)&sBig[row * PITCH + 4 * c4] = src[i];
    }
  }
  __syncthreads();

  const int d = t >> 3, k = t & 7;  // 128 rows x 8 lanes
  if (k < NR) {
    const float4* wrow = (const float4*)&sBig[d * PITCH];
    const float4* w1r  = (const float4*)&sW1T[k * ED];
    float acc = 0.f;
#pragma unroll 8
    for (int jj = 0; jj < ED / 4; ++jj) {
      float4 a = wrow[jj], b = w1r[jj];
      acc = fmaf(a.x, b.x, acc); acc = fmaf(a.y, b.y, acc);
      acc = fmaf(a.z, b.z, acc); acc = fmaf(a.w, b.w, acc);
    }
    sW12T[k * ED + d] = acc;
  }
  __syncthreads();  // sW12T ready; sBig (W2) no longer needed

  {
    const float4* src = (const float4*)Wsw;
    for (int i = t; i < ED * ED / 4; i += 1024) {
      int row = i >> 5, c4 = i & 31;
      *(float4*)&sBig[row * PITCH + 4 * c4] = src[i];
    }
  }
  if (t < 49) {
    int a = t / 7, b = t % 7;
    const float4* ra = (const float4*)&sW12T[a * ED];
    const float4* rb_ = (const float4*)&sW12T[b * ED];
    float q = 0.f;
#pragma unroll 8
    for (int jj = 0; jj < ED / 4; ++jj) {
      float4 x = ra[jj], y = rb_[jj];
      q = fmaf(x.x, y.x, q); q = fmaf(x.y, y.y, q);
      q = fmaf(x.z, y.z, q); q = fmaf(x.w, y.w, q);
    }
    ws[1152 + t] = q;
  } else if (t < 56) {
    int a = t - 49;
    const float4* ra = (const float4*)&sW12T[a * ED];
    float s = 0.f;
#pragma unroll 8
    for (int jj = 0; jj < ED / 4; ++jj) {
      float4 x = ra[jj]; s += x.x + x.y + x.z + x.w;
    }
    ws[1201 + a] = s * (1.f / 128.f);
  }
  __syncthreads();  // sBig now Wsw

  const float4* wrow = (const float4*)&sBig[d * PITCH];
  const float4* g4   = (const float4*)sGB;
  if (k < NR) {
    const float4* w12r = (const float4*)&sW12T[k * ED];
    float m = 0.f;
#pragma unroll 8
    for (int jj = 0; jj < ED / 4; ++jj) {
      float4 a = wrow[jj], g = g4[jj], b = w12r[jj];
      m = fmaf(g.x * a.x, b.x, m); m = fmaf(g.y * a.y, b.y, m);
      m = fmaf(g.z * a.z, b.z, m); m = fmaf(g.w * a.w, b.w, m);
    }
    ws[d * NR + k] = m;
  } else {
    const float4* b4 = (const float4*)&sGB[ED];
    float wsum = 0.f, bb = 0.f;
#pragma unroll 8
    for (int jj = 0; jj < ED / 4; ++jj) {
      float4 a = wrow[jj], g = g4[jj], bt = b4[jj];
      wsum = fmaf(a.x, g.x, wsum); wsum = fmaf(a.y, g.y, wsum);
      wsum = fmaf(a.z, g.z, wsum); wsum = fmaf(a.w, g.w, wsum);
      bb = fmaf(a.x, bt.x, bb); bb = fmaf(a.y, bt.y, bb);
      bb = fmaf(a.z, bt.z, bb); bb = fmaf(a.w, bt.w, bb);
    }
    ws[896 + d] = wsum;
    ws[1024 + d] = bb;
  }
}

__global__ __launch_bounds__(256) void edge_kernel(
    const float* __restrict__ el, const int* __restrict__ u2d,
    const float* __restrict__ ws, float* __restrict__ out)
{
  __shared__ float sQ[56];          // Q[49] then m12[7]
  __shared__ float sRB[256 * 7];    // flat raw pairwise rbf
  __shared__ float sRB3[256 * 7];   // flat raw threebody rbf
  __shared__ float sA[256][8];      // rb*rs [7] + mu*rs
  const int t = threadIdx.x;

  if (t < 56) sQ[t] = ws[1152 + t];

  // Phase-B weights: lane group of 32 covers 128 features, 4 consecutive each.
  const int l = t & 31;
  const int g = t >> 5;
  float M4[4][NR], ws4[4], bb4[4];
#pragma unroll
  for (int c = 0; c < 4; ++c) {
    int d = 4 * l + c;
#pragma unroll
    for (int k = 0; k < NR; ++k) M4[c][k] = ws[d * NR + k];
    ws4[c] = ws[896 + d];
    bb4[c] = ws[1024 + d];
  }

  const int u0 = blockIdx.x * 256;
  const int u  = u0 + t;
  const int nv = (NUND - u0 < 256) ? (NUND - u0) : 256;
  __syncthreads();  // sQ ready

  if (u < NUND) {
    const float r = el[u2d[u]];
    const float invr = 1.f / r;
    const float PI = 3.14159265358979323846f;
    float rb[NR];

    // pairwise RBF, cutoff 6 (raw -> sRB, keep in regs)
    {
      float x = r * (1.f / 6.f);
      float x2 = x * x, x4 = x2 * x2, x8 = x4 * x4;
      float env = fmaf(x8, fmaf(x, fmaf(x, -36.f, 80.f), -45.f), 1.f);
      if (x >= 1.f) env = 0.f;
      float sc = 0.57735026918962576f * env * invr;  // sqrt(2/6)
      float a = PI * x;
      float s1, c1;
      __sincosf(a, &s1, &c1);
      float twoc = 2.f * c1;
      float sm1 = 0.f, s = s1;
#pragma unroll
      for (int k = 0; k < NR; ++k) {
        rb[k] = sc * s;
        sRB[t * 7 + k] = rb[k];
        float nxt = fmaf(twoc, s, -sm1);
        sm1 = s; s = nxt;
      }
    }
    // threebody RBF, cutoff 4 (raw -> sRB3)
    {
      float x = r * 0.25f;
      float x2 = x * x, x4 = x2 * x2, x8 = x4 * x4;
      float env = fmaf(x8, fmaf(x, fmaf(x, -36.f, 80.f), -45.f), 1.f);
      if (x >= 1.f) env = 0.f;
      float sc = 0.70710678118654752f * env * invr;  // sqrt(2/4)
      float a = PI * x;
      float s1, c1;
      __sincosf(a, &s1, &c1);
      float twoc = 2.f * c1;
      float sm1 = 0.f, s = s1;
#pragma unroll
      for (int k = 0; k < NR; ++k) {
        sRB3[t * 7 + k] = sc * s;
        float nxt = fmaf(twoc, s, -sm1);
        sm1 = s; s = nxt;
      }
    }
    // LN stats via bilinear forms
    float mu = 0.f;
#pragma unroll
    for (int k = 0; k < NR; ++k) mu = fmaf(rb[k], sQ[49 + k], mu);
    float msq = 0.f;
#pragma unroll
    for (int k = 0; k < NR; ++k) {
      float acc = 0.f;
#pragma unroll
      for (int k2 = 0; k2 < NR; ++k2) acc = fmaf(sQ[k * 7 + k2], rb[k2], acc);
      msq = fmaf(rb[k], acc, msq);
    }
    float var = fmaf(msq, (1.f / 128.f), -mu * mu);
    float rs = rsqrtf(var + 1e-5f);
    float4 lo, hi;
    lo.x = rb[0] * rs; lo.y = rb[1] * rs; lo.z = rb[2] * rs; lo.w = rb[3] * rs;
    hi.x = rb[4] * rs; hi.y = rb[5] * rs; hi.z = rb[6] * rs; hi.w = mu * rs;
    *(float4*)&sA[t][0] = lo;   // ds_write_b128, conflict-free
    *(float4*)&sA[t][4] = hi;
  }
  __syncthreads();  // sRB/sRB3/sA ready

  // Coalesced NT float4 stores of both RBF blocks (contiguous [nv*7] each).
  {
    float* outP = out + (size_t)64000000 + (size_t)u0 * 7;
    float* outT = out + (size_t)67500000 + (size_t)u0 * 7;
    const int total = nv * 7;
    const int n4 = total >> 2;
    for (int i = t; i < n4; i += 256) {
      fx4 v = *(const fx4*)&sRB[4 * i];
      __builtin_nontemporal_store(v, (fx4*)&outP[4 * i]);
      fx4 w = *(const fx4*)&sRB3[4 * i];
      __builtin_nontemporal_store(w, (fx4*)&outT[4 * i]);
    }
    for (int i = 4 * n4 + t; i < total; i += 256) {  // empty for nv=256/32
      __builtin_nontemporal_store(sRB[i], &outP[i]);
      __builtin_nontemporal_store(sRB3[i], &outT[i]);
    }
  }

  // Phase B: 8 edges in flight, each lane NT-stores one float4.
  for (int eb = 0; eb < 256; eb += 8) {
    int e = eb + g;
    if (e < nv) {
      float4 v0 = *(const float4*)&sA[e][0];
      float4 v1 = *(const float4*)&sA[e][4];
      fx4 res;
#pragma unroll
      for (int c = 0; c < 4; ++c) {
        float pre = fmaf(-v1.w, ws4[c], bb4[c]);
        pre = fmaf(v0.x, M4[c][0], pre);
        pre = fmaf(v0.y, M4[c][1], pre);
        pre = fmaf(v0.z, M4[c][2], pre);
        pre = fmaf(v0.w, M4[c][3], pre);
        pre = fmaf(v1.x, M4[c][4], pre);
        pre = fmaf(v1.y, M4[c][5], pre);
        pre = fmaf(v1.z, M4[c][6], pre);
        float sig = 1.f / (1.f + __expf(-pre));
        res[c] = pre * sig;
      }
      __builtin_nontemporal_store(res, (fx4*)&out[(size_t)(u0 + e) * 128 + 4 * l]);
    }
  }
}

extern "C" void kernel_launch(void* const* d_in, const int* in_sizes, int n_in,
                              void* d_out, int out_size, void* d_ws, size_t ws_size,
                              hipStream_t stream) {
  const float* edge_lengths = (const float*)d_in[0];
  const int*   u2d          = (const int*)d_in[1];
  // d_in[2] = directed2undirected — not needed (segment mean of identical rows)
  const float* W1    = (const float*)d_in[3];
  const float* W2    = (const float*)d_in[4];
  const float* gamma = (const float*)d_in[5];
  const float* beta  = (const float*)d_in[6];
  const float* Wsw   = (const float*)d_in[7];
  float* out = (float*)d_out;
  float* ws  = (float*)d_ws;

  hipLaunchKernelGGL(precompute_kernel, dim3(1), dim3(1024), 0, stream,
                     W1, W2, gamma, beta, Wsw, ws);
  const int nblk = (NUND + 255) / 256;  // 1954
  hipLaunchKernelGGL(edge_kernel, dim3(nblk), dim3(256), 0, stream,
                     edge_lengths, u2d, ws, out);
}